// Round 1
// baseline (262.394 us; speedup 1.0000x reference)
//
#include <hip/hip_runtime.h>
#include <math.h>

// Problem constants: B=8, CIN=COUT=128, H=W=Ho=Wo=64, KH=KW=3 (K=9),
// stride=pad=dil=1, EPS=1e-4.
//
// Pipeline:
//   wnorm_k : wn[k][c][o] = w[o][c][k] / (3*sqrt(sum_c w^2 + 128*EPS))
//   xpose_k : xt[b][h][w][c] = x[b][c][h][w]   (channel-last for coalesced bilinear gathers)
//   dconv_k : fused bilinear-im2col + GEMM (M=128 cout, K=1152, N=64 pixels/block)

__global__ void wnorm_k(const float* __restrict__ w, float* __restrict__ wn) {
    const int ok = blockIdx.x;          // 0..1151 = o*9 + k
    const int o = ok / 9, k = ok % 9;
    const int lane = threadIdx.x;       // 64 threads = 1 wave
    const float v0 = w[o * 1152 + lane * 9 + k];
    const float v1 = w[o * 1152 + (lane + 64) * 9 + k];
    float s = v0 * v0 + v1 * v1;
    #pragma unroll
    for (int d = 32; d >= 1; d >>= 1) s += __shfl_xor(s, d, 64);
    const float inv = 1.0f / (3.0f * sqrtf(s + 128.0f * 1e-4f));
    wn[(k * 128 + lane) * 128 + o]        = v0 * inv;
    wn[(k * 128 + (lane + 64)) * 128 + o] = v1 * inv;
}

__global__ void xpose_k(const float* __restrict__ x, float* __restrict__ xt) {
    __shared__ float lds[128 * 65];     // +1 pad breaks the power-of-2 stride
    const int b = blockIdx.x >> 6, h = blockIdx.x & 63;
    const int tid = threadIdx.x;        // 256
    const float* xp = x + (b * 128 * 64 + h) * 64;   // + c*4096 + w
    #pragma unroll 4
    for (int i = 0; i < 32; i++) {
        const int c = i * 4 + (tid >> 6);
        const int ww = tid & 63;
        lds[c * 65 + ww] = xp[c * 4096 + ww];        // coalesced 256B per wave
    }
    __syncthreads();
    float* xo = xt + blockIdx.x * 8192;              // [b][h][w][c]
    #pragma unroll 4
    for (int i = 0; i < 32; i++) {
        const int flat = i * 256 + tid;              // w*128 + c
        xo[flat] = lds[(flat & 127) * 65 + (flat >> 7)];  // conflict-free, coalesced store
    }
}

__global__ __launch_bounds__(256, 2) void dconv_k(
    const float* __restrict__ xt, const float* __restrict__ off,
    const float* __restrict__ wng, float* __restrict__ out)
{
    // LDS budget: 9.2 + 9.2 + 17.4 + 32.8 KB = ~68 KB -> 2 blocks/CU (512 blocks = 2/CU exactly)
    __shared__ float4 tapw[576];          // [k][p] bilinear corner weights (validity folded in)
    __shared__ int4   tapi[576];          // [k][p] pre-clamped corner offsets (*128 ch)
    __shared__ float  colsS[64 * 68];     // [p][c-tile], stride 68 (16B-aligned rows)
    __shared__ float  wnlS[64 * 128];     // [c-tile][o]

    const int bh = blockIdx.x;            // b*64 + ho
    const int b = bh >> 6, ho = bh & 63;
    const int tid = threadIdx.x;

    // ---- Per-block tap geometry precompute (576 = 9 taps x 64 pixels) ----
    for (int t = tid; t < 576; t += 256) {
        const int k = t >> 6, p = t & 63;
        const int oidx = ((b * 18 + 2 * k) * 64 + ho) * 64 + p;
        const float offy = off[oidx];
        const float offx = off[oidx + 4096];        // channel 2k+1
        const float py = (float)(ho - 1 + (k / 3)) + offy;
        const float px = (float)(p - 1 + (k % 3)) + offx;
        const float y0f = floorf(py), x0f = floorf(px);
        const float ly = py - y0f, lx = px - x0f;
        const int y0 = (int)y0f, x0 = (int)x0f;
        const int y1 = y0 + 1, x1 = x0 + 1;
        const float vy0 = (y0 >= 0 && y0 < 64) ? 1.0f : 0.0f;
        const float vy1 = (y1 >= 0 && y1 < 64) ? 1.0f : 0.0f;
        const float vx0 = (x0 >= 0 && x0 < 64) ? 1.0f : 0.0f;
        const float vx1 = (x1 >= 0 && x1 < 64) ? 1.0f : 0.0f;
        const int yc0 = min(max(y0, 0), 63), yc1 = min(max(y1, 0), 63);
        const int xc0 = min(max(x0, 0), 63), xc1 = min(max(x1, 0), 63);
        tapw[t] = make_float4((1.0f - ly) * (1.0f - lx) * vy0 * vx0,
                              (1.0f - ly) * lx          * vy0 * vx1,
                              ly * (1.0f - lx)          * vy1 * vx0,
                              ly * lx                   * vy1 * vx1);
        tapi[t] = make_int4((yc0 * 64 + xc0) * 128, (yc0 * 64 + xc1) * 128,
                            (yc1 * 64 + xc0) * 128, (yc1 * 64 + xc1) * 128);
    }
    __syncthreads();

    // Thread tile: 4 cout x 8 pixels
    const int ot = tid & 31, pt = tid >> 5;
    const int obase = ot * 4, pbase = pt * 8;
    float acc[4][8];
    #pragma unroll
    for (int i = 0; i < 4; i++)
        #pragma unroll
        for (int p = 0; p < 8; p++) acc[i][p] = 0.0f;

    const float* xb = xt + b * (64 * 64 * 128);
    const int cl = tid & 63, psub = tid >> 6;

    for (int k = 0; k < 9; k++) {
        for (int ch = 0; ch < 2; ch++) {
            // Stage wn tile [64c][128o] (coalesced float4)
            const float* wsrc = wng + (k * 128 + ch * 64) * 128;
            #pragma unroll
            for (int i = 0; i < 8; i++)
                *(float4*)&wnlS[i * 1024 + tid * 4] =
                    *(const float4*)&wsrc[i * 1024 + tid * 4];

            // Build cols tile [64p][64c]: 4 pixels in flight, lanes = channels (coalesced)
            const int cg = ch * 64 + cl;
            #pragma unroll 4
            for (int i = 0; i < 16; i++) {
                const int p = i * 4 + psub;
                const float4 wv = tapw[k * 64 + p];
                const int4  iv = tapi[k * 64 + p];
                colsS[p * 68 + cl] = wv.x * xb[iv.x + cg] + wv.y * xb[iv.y + cg]
                                   + wv.z * xb[iv.z + cg] + wv.w * xb[iv.w + cg];
            }
            __syncthreads();

            // GEMM micro-kernel: 12 x ds_read_b128 per 128 FMA -> VALU-bound
            #pragma unroll 2
            for (int c4 = 0; c4 < 64; c4 += 4) {
                const float4 w0 = *(const float4*)&wnlS[(c4 + 0) * 128 + obase];
                const float4 w1 = *(const float4*)&wnlS[(c4 + 1) * 128 + obase];
                const float4 w2 = *(const float4*)&wnlS[(c4 + 2) * 128 + obase];
                const float4 w3 = *(const float4*)&wnlS[(c4 + 3) * 128 + obase];
                #pragma unroll
                for (int p = 0; p < 8; p++) {
                    const float4 cv = *(const float4*)&colsS[(pbase + p) * 68 + c4];
                    acc[0][p] += w0.x * cv.x + w1.x * cv.y + w2.x * cv.z + w3.x * cv.w;
                    acc[1][p] += w0.y * cv.x + w1.y * cv.y + w2.y * cv.z + w3.y * cv.w;
                    acc[2][p] += w0.z * cv.x + w1.z * cv.y + w2.z * cv.z + w3.z * cv.w;
                    acc[3][p] += w0.w * cv.x + w1.w * cv.y + w2.w * cv.z + w3.w * cv.w;
                }
            }
            __syncthreads();
        }
    }

    // Epilogue: out[b][o][ho][wo]
    float* ob = out + (b * 128) * 4096 + ho * 64;
    #pragma unroll
    for (int i = 0; i < 4; i++)
        #pragma unroll
        for (int p = 0; p < 8; p++)
            ob[(obase + i) * 4096 + pbase + p] = acc[i][p];
}

extern "C" void kernel_launch(void* const* d_in, const int* in_sizes, int n_in,
                              void* d_out, int out_size, void* d_ws, size_t ws_size,
                              hipStream_t stream) {
    const float* x   = (const float*)d_in[0];   // [8][128][64][64]
    const float* off = (const float*)d_in[1];   // [8][18][64][64]
    const float* w   = (const float*)d_in[2];   // [128][128][3][3]
    float* out = (float*)d_out;                 // [8][128][64][64]

    float* wn = (float*)d_ws;                   // 147456 floats: wn[k][c][o]
    float* xt = wn + 1152 * 128;                // 4194304 floats: xt[b][h][w][c]

    hipLaunchKernelGGL(wnorm_k, dim3(1152), dim3(64),  0, stream, w, wn);
    hipLaunchKernelGGL(xpose_k, dim3(512),  dim3(256), 0, stream, x, xt);
    hipLaunchKernelGGL(dconv_k, dim3(512),  dim3(256), 0, stream, xt, off, wn, out);
}

// Round 2
// 106.317 us; speedup vs baseline: 2.4680x; 2.4680x over previous
//
#include <hip/hip_runtime.h>
#include <math.h>

// B=8, CIN=COUT=128, H=W=Ho=Wo=64, K=9, stride=pad=dil=1, EPS=1e-4.
//
// Pipeline:
//   wnorm_k : wn[o][c][k] normalized -> bf16, pre-swizzled into MFMA A-fragment
//             order wb[k][c/8][cout][c%8]
//   xpose_k : x[b][c][h][w] fp32 -> xt[b][h][w][c] bf16 (channel-last, 16B/octet
//             bilinear corner loads)
//   dconv_k : fused bilinear-im2col (fp32 math, bf16 in/out) + MFMA GEMM
//             (16x16x32 bf16), block = one (b,ho) row: 64 pix x 128 cout, K=1152

typedef __attribute__((ext_vector_type(8))) short short8;   // 8 bf16 = 4 VGPRs
typedef __attribute__((ext_vector_type(4))) float floatx4;

static __device__ __forceinline__ unsigned int f2bf(float f) {
    unsigned int u = __float_as_uint(f);
    u += 0x7fffu + ((u >> 16) & 1u);          // round-to-nearest-even
    return u >> 16;
}
static __device__ __forceinline__ float bflo(unsigned int w) {
    return __uint_as_float(w << 16);
}
static __device__ __forceinline__ float bfhi(unsigned int w) {
    return __uint_as_float(w & 0xffff0000u);
}

__global__ void wnorm_k(const float* __restrict__ w, unsigned short* __restrict__ wb) {
    const int ok = blockIdx.x;          // o*9 + k
    const int o = ok / 9, k = ok % 9;
    const int lane = threadIdx.x;       // 64 = 1 wave; lane = c, lane+64 = c
    const float v0 = w[o * 1152 + lane * 9 + k];
    const float v1 = w[o * 1152 + (lane + 64) * 9 + k];
    float s = v0 * v0 + v1 * v1;
    #pragma unroll
    for (int d = 32; d >= 1; d >>= 1) s += __shfl_xor(s, d, 64);
    const float inv = 1.0f / (3.0f * sqrtf(s + 0.0128f));   // 128*EPS
    // wb[k][c>>3][o][c&7]
    wb[((k * 16 + (lane >> 3)) * 128 + o) * 8 + (lane & 7)]     = (unsigned short)f2bf(v0 * inv);
    wb[((k * 16 + 8 + (lane >> 3)) * 128 + o) * 8 + (lane & 7)] = (unsigned short)f2bf(v1 * inv);
}

__global__ void xpose_k(const float* __restrict__ x, unsigned int* __restrict__ xt32) {
    __shared__ float lds[128 * 65];
    const int b = blockIdx.x >> 6, h = blockIdx.x & 63;
    const int tid = threadIdx.x;        // 256
    const float* xp = x + (b * 128 * 64 + h) * 64;
    #pragma unroll 4
    for (int i = 0; i < 32; i++) {
        const int c = i * 4 + (tid >> 6);
        const int ww = tid & 63;
        lds[c * 65 + ww] = xp[c * 4096 + ww];
    }
    __syncthreads();
    unsigned int* xo = xt32 + blockIdx.x * 4096;   // [b][h][w][c/2] packed pairs
    #pragma unroll 4
    for (int i = 0; i < 16; i++) {
        const int flat2 = i * 256 + tid;           // w*64 + cpair
        const int ww = flat2 >> 6, cp = flat2 & 63;
        const unsigned int lo = f2bf(lds[(2 * cp) * 65 + ww]);
        const unsigned int hi = f2bf(lds[(2 * cp + 1) * 65 + ww]);
        xo[flat2] = lo | (hi << 16);
    }
}

__global__ __launch_bounds__(256, 2) void dconv_k(
    const unsigned short* __restrict__ xt, const float* __restrict__ off,
    const unsigned short* __restrict__ wb, float* __restrict__ out)
{
    // LDS: 9216 + 9216 + 16640 + 32768 = 67840 B -> 2 blocks/CU (512 blocks total)
    __shared__ float4 tapw[576];                       // [k][p] corner weights
    __shared__ int4   tapi[576];                       // [k][p] corner offsets (bf16 elems)
    __shared__ alignas(16) unsigned short colsS[16 * 520];  // [c/8][pix][8], +8el row pad
    __shared__ alignas(16) unsigned short wS[16 * 128 * 8]; // [c/8][cout][8]

    const int bh = blockIdx.x, b = bh >> 6, ho = bh & 63;
    const int tid = threadIdx.x;

    // ---- tap geometry: 576 = 9 taps x 64 pixels ----
    for (int t = tid; t < 576; t += 256) {
        const int k = t >> 6, p = t & 63;
        const int oidx = ((b * 18 + 2 * k) * 64 + ho) * 64 + p;
        const float offy = off[oidx];
        const float offx = off[oidx + 4096];
        const float py = (float)(ho - 1 + (k / 3)) + offy;
        const float px = (float)(p - 1 + (k % 3)) + offx;
        const float y0f = floorf(py), x0f = floorf(px);
        const float ly = py - y0f, lx = px - x0f;
        const int y0 = (int)y0f, x0 = (int)x0f;
        const int y1 = y0 + 1, x1 = x0 + 1;
        const float vy0 = (y0 >= 0 && y0 < 64) ? 1.0f : 0.0f;
        const float vy1 = (y1 >= 0 && y1 < 64) ? 1.0f : 0.0f;
        const float vx0 = (x0 >= 0 && x0 < 64) ? 1.0f : 0.0f;
        const float vx1 = (x1 >= 0 && x1 < 64) ? 1.0f : 0.0f;
        const int yc0 = min(max(y0, 0), 63), yc1 = min(max(y1, 0), 63);
        const int xc0 = min(max(x0, 0), 63), xc1 = min(max(x1, 0), 63);
        tapw[t] = make_float4((1.0f - ly) * (1.0f - lx) * vy0 * vx0,
                              (1.0f - ly) * lx          * vy0 * vx1,
                              ly * (1.0f - lx)          * vy1 * vx0,
                              ly * lx                   * vy1 * vx1);
        tapi[t] = make_int4((yc0 * 64 + xc0) * 128, (yc0 * 64 + xc1) * 128,
                            (yc1 * 64 + xc0) * 128, (yc1 * 64 + xc1) * 128);
    }
    __syncthreads();

    const int lane = tid & 63, wv = tid >> 6;
    const int quad = lane >> 4, l16 = lane & 15;
    const int g = tid & 15, prow = tid >> 4;      // gather: c-octet, pixel row
    const unsigned short* xb = xt + b * (64 * 64 * 128);
    const int wbase = wv * 32;                    // wave's cout base

    floatx4 acc0[4], acc1[4];
    #pragma unroll
    for (int t = 0; t < 4; t++) {
        acc0[t] = (floatx4)0.0f;
        acc1[t] = (floatx4)0.0f;
    }

    for (int k = 0; k < 9; k++) {
        // stage this tap's weights: straight 32KB copy (pre-swizzled by wnorm_k)
        const uint4* wsrc = (const uint4*)(wb + k * 16384);
        uint4* wdst = (uint4*)wS;
        #pragma unroll
        for (int i = 0; i < 8; i++) wdst[i * 256 + tid] = wsrc[i * 256 + tid];

        // bilinear gather: each thread = 8 channels x 4 pixels, fp32 math
        #pragma unroll
        for (int i = 0; i < 4; i++) {
            const int p = i * 16 + prow;
            const float4 wvv = tapw[k * 64 + p];
            const int4  iv  = tapi[k * 64 + p];
            const uint4 r0 = *(const uint4*)(xb + iv.x + g * 8);
            const uint4 r1 = *(const uint4*)(xb + iv.y + g * 8);
            const uint4 r2 = *(const uint4*)(xb + iv.z + g * 8);
            const uint4 r3 = *(const uint4*)(xb + iv.w + g * 8);
            uint4 pk;
            {
                const float lo = wvv.x*bflo(r0.x) + wvv.y*bflo(r1.x) + wvv.z*bflo(r2.x) + wvv.w*bflo(r3.x);
                const float hi = wvv.x*bfhi(r0.x) + wvv.y*bfhi(r1.x) + wvv.z*bfhi(r2.x) + wvv.w*bfhi(r3.x);
                pk.x = f2bf(lo) | (f2bf(hi) << 16);
            }
            {
                const float lo = wvv.x*bflo(r0.y) + wvv.y*bflo(r1.y) + wvv.z*bflo(r2.y) + wvv.w*bflo(r3.y);
                const float hi = wvv.x*bfhi(r0.y) + wvv.y*bfhi(r1.y) + wvv.z*bfhi(r2.y) + wvv.w*bfhi(r3.y);
                pk.y = f2bf(lo) | (f2bf(hi) << 16);
            }
            {
                const float lo = wvv.x*bflo(r0.z) + wvv.y*bflo(r1.z) + wvv.z*bflo(r2.z) + wvv.w*bflo(r3.z);
                const float hi = wvv.x*bfhi(r0.z) + wvv.y*bfhi(r1.z) + wvv.z*bfhi(r2.z) + wvv.w*bfhi(r3.z);
                pk.z = f2bf(lo) | (f2bf(hi) << 16);
            }
            {
                const float lo = wvv.x*bflo(r0.w) + wvv.y*bflo(r1.w) + wvv.z*bflo(r2.w) + wvv.w*bflo(r3.w);
                const float hi = wvv.x*bfhi(r0.w) + wvv.y*bfhi(r1.w) + wvv.z*bfhi(r2.w) + wvv.w*bfhi(r3.w);
                pk.w = f2bf(lo) | (f2bf(hi) << 16);
            }
            *(uint4*)&colsS[g * 520 + p * 8] = pk;   // [c/8][pix][8]
        }
        __syncthreads();

        // MFMA: wave = 32 cout x 64 pix; A = weights, B = cols
        #pragma unroll
        for (int q = 0; q < 4; q++) {
            const int cgrp = q * 4 + quad;
            const short8 a0 = *(const short8*)&wS[(cgrp * 128 + wbase + l16) * 8];
            const short8 a1 = *(const short8*)&wS[(cgrp * 128 + wbase + 16 + l16) * 8];
            #pragma unroll
            for (int t = 0; t < 4; t++) {
                const short8 bf = *(const short8*)&colsS[cgrp * 520 + (t * 16 + l16) * 8];
                acc0[t] = __builtin_amdgcn_mfma_f32_16x16x32_bf16(a0, bf, acc0[t], 0, 0, 0);
                acc1[t] = __builtin_amdgcn_mfma_f32_16x16x32_bf16(a1, bf, acc1[t], 0, 0, 0);
            }
        }
        __syncthreads();
    }

    // epilogue: C/D layout col(=pixel)=lane&15, row(=cout)=quad*4+reg
    float* ob = out + b * 128 * 4096 + ho * 64;
    #pragma unroll
    for (int t = 0; t < 4; t++) {
        const int pix = t * 16 + l16;
        #pragma unroll
        for (int r = 0; r < 4; r++) {
            ob[(wbase + quad * 4 + r) * 4096 + pix]      = acc0[t][r];
            ob[(wbase + 16 + quad * 4 + r) * 4096 + pix] = acc1[t][r];
        }
    }
}

extern "C" void kernel_launch(void* const* d_in, const int* in_sizes, int n_in,
                              void* d_out, int out_size, void* d_ws, size_t ws_size,
                              hipStream_t stream) {
    const float* x   = (const float*)d_in[0];   // [8][128][64][64]
    const float* off = (const float*)d_in[1];   // [8][18][64][64]
    const float* w   = (const float*)d_in[2];   // [128][128][3][3]
    float* out = (float*)d_out;                 // [8][128][64][64]

    unsigned short* xt = (unsigned short*)d_ws;          // 4,194,304 bf16 = 8 MiB
    unsigned short* wbuf = xt + 8 * 64 * 64 * 128;       // 147,456 bf16

    hipLaunchKernelGGL(wnorm_k, dim3(1152), dim3(64),  0, stream, w, wbuf);
    hipLaunchKernelGGL(xpose_k, dim3(512),  dim3(256), 0, stream, x, (unsigned int*)xt);
    hipLaunchKernelGGL(dconv_k, dim3(512),  dim3(256), 0, stream, xt, off, wbuf, out);
}